// Round 9
// baseline (272.349 us; speedup 1.0000x reference)
//
#include <hip/hip_runtime.h>
#include <hip/hip_bf16.h>

using bf16 = __hip_bfloat16;

typedef __attribute__((ext_vector_type(8))) __bf16 bf16x8;
typedef __attribute__((ext_vector_type(4))) float floatx4;

#define EPS 1e-6f

#define RAW_BARRIER()  asm volatile("s_barrier" ::: "memory")
#define WAIT_VM16()    asm volatile("s_waitcnt vmcnt(16)" ::: "memory")
#define WAIT_VM8()     asm volatile("s_waitcnt vmcnt(8)" ::: "memory")
#define WAIT_VM4()     asm volatile("s_waitcnt vmcnt(4)" ::: "memory")
#define WAIT_VM0()     asm volatile("s_waitcnt vmcnt(0)" ::: "memory")
#define SCHED_FENCE()  __builtin_amdgcn_sched_barrier(0)
#define PRIO1()        __builtin_amdgcn_s_setprio(1)
#define PRIO0()        __builtin_amdgcn_s_setprio(0)

__device__ __forceinline__ void load_lds16(const void* g, void* l) {
    __builtin_amdgcn_global_load_lds(
        (const __attribute__((address_space(1))) void*)g,
        (__attribute__((address_space(3))) void*)l, 16, 0, 0);
}

__device__ __forceinline__ void storeOut(float* p, float v) { *p = v; }
__device__ __forceinline__ void storeOut(bf16* p, float v) { *p = __float2bfloat16(v); }

#define MFMA16(a, b, c) __builtin_amdgcn_mfma_f32_16x16x32_bf16(a, b, c, 0, 0, 0)

// ---------------------------------------------------------------------------
// 2-blocks/CU pipelined NT GEMM: D[m][n] = sum_k A[m][k] * B[n][k]
// BM=BN=128, BK=64 (k-half split), 256 threads = 4 waves (2M x 2N).
// (Unchanged — used for QKV projection and output projection.)
// ---------------------------------------------------------------------------
template <int BIAS_MODE, int RESID_EN, int QKV, typename OutT>
__global__ __launch_bounds__(256, 2) void gemm2b(
    const bf16* __restrict__ A, long long aStride, int lda,
    const bf16* __restrict__ B, long long bStride, int ldb,
    OutT* __restrict__ D, long long dStride, int ldd,
    bf16* __restrict__ vout, long long vStride,
    const float* __restrict__ bias,
    const float* __restrict__ resid, long long rStride, int ldr,
    int K, int tpb, int gx)
{
    constexpr int HB = 8192;   // bytes per (buf, khalf) per operand: 128x32x2B
    extern __shared__ char smem[];

    const unsigned chunk = gridDim.x >> 3;
    const unsigned glob  = (blockIdx.x & 7) * chunk + (blockIdx.x >> 3);
    const unsigned z  = glob / (unsigned)tpb;
    const unsigned t  = glob % (unsigned)tpb;
    const int m0 = (int)(t / (unsigned)gx) << 7;
    const int n0 = (int)(t % (unsigned)gx) << 7;

    const int tid  = threadIdx.x;
    const int lane = tid & 63;
    const int wave = tid >> 6;
    const int wm   = wave >> 1;          // 0..1
    const int wn   = wave & 1;           // 0..1

    const bf16* Ab = A + (size_t)z * aStride + (size_t)m0 * lda;
    const bf16* Bb = B + (size_t)z * bStride + (size_t)n0 * ldb;

    floatx4 acc[4][4];
#pragma unroll
    for (int i = 0; i < 4; ++i)
#pragma unroll
        for (int j = 0; j < 4; ++j) acc[i][j] = (floatx4){0.f, 0.f, 0.f, 0.f};

    const int laneRow = lane & 15;
    const int laneKq  = lane >> 4;
    const int kqs16   = (laneKq ^ ((laneRow >> 1) & 3)) << 4;
    const int arow0   = wm * 64 + laneRow;
    const int brow0   = wn * 64 + laneRow;

    auto stage = [&](int kt, int h) {
        char* Adst = smem + ((kt & 1) * 2 + h) * HB;
        char* Bdst = smem + 4 * HB + ((kt & 1) * 2 + h) * HB;
        const int kb = (kt << 6) + (h << 5);
#pragma unroll
        for (int u = 0; u < 2; ++u) {
            const int idx = tid + u * 256;
            const int r  = idx >> 2;
            const int qs = (idx & 3) ^ ((idx >> 3) & 3);
            load_lds16(Ab + (size_t)r * lda + kb + qs * 8, Adst + idx * 16);
        }
#pragma unroll
        for (int u = 0; u < 2; ++u) {
            const int idx = tid + u * 256;
            const int r  = idx >> 2;
            const int qs = (idx & 3) ^ ((idx >> 3) & 3);
            load_lds16(Bb + (size_t)r * ldb + kb + qs * 8, Bdst + idx * 16);
        }
    };

    const int nt = K >> 6;
    stage(0, 0); stage(0, 1); stage(1, 0);

    for (int kt = 0; kt < nt; ++kt) {
        const char* Ablk = smem + (kt & 1) * 2 * HB;
        const char* Bblk = smem + 4 * HB + (kt & 1) * 2 * HB;
        const bool lastT = (kt == nt - 1);

        // ---- phase 1: k-half 0 ----
        if (lastT) WAIT_VM4(); else WAIT_VM8();
        RAW_BARRIER();
        bf16x8 af[4], bfr[4];
#pragma unroll
        for (int im = 0; im < 4; ++im)
            af[im] = *(const bf16x8*)(Ablk + (arow0 + im * 16) * 64 + kqs16);
#pragma unroll
        for (int in = 0; in < 4; ++in)
            bfr[in] = *(const bf16x8*)(Bblk + (brow0 + in * 16) * 64 + kqs16);
        if (kt + 1 < nt) stage(kt + 1, 1);
        RAW_BARRIER();
        PRIO1();
#pragma unroll
        for (int im = 0; im < 4; ++im)
#pragma unroll
            for (int in = 0; in < 4; ++in)
                acc[im][in] = MFMA16(af[im], bfr[in], acc[im][in]);
        PRIO0();

        // ---- phase 2: k-half 1 ----
        if (lastT) WAIT_VM0(); else WAIT_VM8();
        RAW_BARRIER();
#pragma unroll
        for (int im = 0; im < 4; ++im)
            af[im] = *(const bf16x8*)(Ablk + HB + (arow0 + im * 16) * 64 + kqs16);
#pragma unroll
        for (int in = 0; in < 4; ++in)
            bfr[in] = *(const bf16x8*)(Bblk + HB + (brow0 + in * 16) * 64 + kqs16);
        if (kt + 2 < nt) stage(kt + 2, 0);
        RAW_BARRIER();
        PRIO1();
#pragma unroll
        for (int im = 0; im < 4; ++im)
#pragma unroll
            for (int in = 0; in < 4; ++in)
                acc[im][in] = MFMA16(af[im], bfr[in], acc[im][in]);
        PRIO0();
    }

    // Epilogue. C/D frag layout: col = lane&15, row = (lane>>4)*4 + reg
    const size_t dbase = (size_t)z * dStride;
#pragma unroll
    for (int im = 0; im < 4; ++im) {
        const int gmb = m0 + wm * 64 + im * 16 + (laneKq << 2);
#pragma unroll
        for (int in = 0; in < 4; ++in) {
            const int gn = n0 + wn * 64 + in * 16 + laneRow;
            float bn = 0.f;
            if (BIAS_MODE == 2) bn = bias[gn];
            if (QKV && n0 >= 1024) {
                union { bf16 h[4]; ushort4 u; } pk;
#pragma unroll
                for (int r = 0; r < 4; ++r)
                    pk.h[r] = __float2bfloat16(acc[im][in][r] + bn);
                *(ushort4*)(vout + (size_t)z * vStride +
                            (size_t)(gn - 1024) * 1024 + gmb) = pk.u;
            } else {
#pragma unroll
                for (int r = 0; r < 4; ++r) {
                    const int gm = gmb + r;
                    float v = acc[im][in][r];
                    if (BIAS_MODE == 1) v += bias[gm];
                    if (BIAS_MODE == 2) v += bn;
                    if (RESID_EN)
                        v += resid[(size_t)z * rStride + (size_t)gm * ldr + gn];
                    storeOut(D + dbase + (size_t)gm * ldd + gn, v);
                }
            }
        }
    }
}

// ---------------------------------------------------------------------------
// Fused attention v5 = v4's c-split + 2 blocks/CU.
//   S'[j][i] = K_j . Q_i (swapped), P = exp(scale*S'), rowsum[i] += P,
//   O[c][i] += V[c][j] * P[j][i], O2[i][c] = O / rowsum.
// v4 (74.2us) was latency-bound at 1 wave/SIMD (Occupancy 10%): 5566 cy/tile
// vs ~2800 cy LDS model. v5 gets cross-wave overlap:
//  - Block = 32 q-rows; grid 512 = 2 blocks/CU (LDS 64KB each).
//  - Only K lives in LDS (2 x 32KB double buffer). V is read DIRECTLY from
//    L2 into registers: c-split means each wave loads only its own 128-c
//    slice (8 x 1KB coalesced wave-loads = 16 full lines each, no
//    duplication — unlike R5/R6 which globalized 4x-duplicated reads).
//  - QK split by (jh, ih): wave computes S'[16 j][16 i] with 16 kf reads
//    (K LDS reads halve vs v4) + 16-chain MFMA. qf = 16 frags for its
//    16 i-rows.
//  - P write: 1 b64/lane at strip ih, row laneRow, granule (4jh+laneKq)^sw2
//    (same involution as v4's verified pair: bit0 preserved, bits[2:1] =
//    (q4>>1)^m). Read side unchanged (pf[ni] at kqs16).
//  - vmcnt ledger (issue order: ... K(t) | V(t), K(t+1) | V(t+1), K(t+2)):
//    top-of-tile vmcnt(16) retires K(t); pre-PV vmcnt(8) retires V(t),
//    leaves K(t+1) in flight; t=31: vmcnt(8) / vmcnt(0).
//  - __launch_bounds__(256,2): cap VGPR at 256 for 2 waves/SIMD.
//    Live set ~190: qf 64 + acc[8][2] 64 + vf 32 + temps.
// rowsum now needs a jh-sum: rsLDS[2][32], summed in epilogue.
// ---------------------------------------------------------------------------
__global__ __launch_bounds__(256, 2) void fattn(
    const bf16* __restrict__ qkT,   // (B,1024,1024): row i = [q_i | k_i]
    const bf16* __restrict__ vv,    // (B,512,1024): [c][j]
    bf16* __restrict__ O2,          // (B,1024,512): [i][c]
    float scale)
{
    constexpr int KT = 32768;           // one K-tile: 32j x 512k bf16 = 32KB
    extern __shared__ char smem[];      // 2 x KT (K double buffer) = 64KB
    __shared__ __align__(16) char plds[2048];   // P: 2 strips x [16 i][32 j]
    __shared__ float rsLDS[2][32];

    const int bid  = blockIdx.x;
    const int glob = (bid & 7) * 64 + (bid >> 3);   // XCD-chunked (512 blocks)
    const int b    = glob >> 5;
    const int i0   = (glob & 31) << 5;              // 32-row i-tile

    const int tid     = threadIdx.x;
    const int lane    = tid & 63;
    const int wave    = tid >> 6;
    const int jh      = wave >> 1;      // j-half owner in QK
    const int ih      = wave & 1;       // i-half owner in QK
    const int laneRow = lane & 15;
    const int laneKq  = lane >> 4;
    const int kqs16   = (laneKq ^ ((laneRow >> 1) & 3)) << 4;
    const int sw2     = ((laneRow >> 1) & 3) << 1;  // 8B-granule XOR mask

    const bf16* Qb = qkT + (size_t)b * 1048576 +
                     (size_t)(i0 + ih * 16 + laneRow) * 1024;
    const bf16* Kb = qkT + (size_t)b * 1048576 + 512;
    // V slice for PV: c = wave*128 + mf*16 + laneRow, j-cols laneKq*8..+8
    const bf16* Vb = vv + (size_t)b * 524288 +
                     (size_t)(wave * 128 + laneRow) * 1024 + laneKq * 8;

    // Q fragments: i = i0 + 16*ih + laneRow, k = ks*32 + laneKq*8..+8
    bf16x8 qf[16];
#pragma unroll
    for (int ks = 0; ks < 16; ++ks)
        qf[ks] = *(const bf16x8*)(Qb + ks * 32 + laneKq * 8);

    // acc[mf][ni]: c = wave*128 + mf*16 + 4*laneKq + r, i = 16*ni + laneRow
    floatx4 acc[8][2];
#pragma unroll
    for (int mf = 0; mf < 8; ++mf)
#pragma unroll
        for (int ni = 0; ni < 2; ++ni) acc[mf][ni] = (floatx4){0.f, 0.f, 0.f, 0.f};
    float rs = 0.f;

    auto stageK = [&](int jt) {
        char* dst = smem + (jt & 1) * KT;
        const bf16* src = Kb + ((size_t)jt << 5) * 1024;
#pragma unroll
        for (int u = 0; u < 8; ++u) {
            const int idx = tid + u * 256;          // 0..2047
            const int kk = idx >> 7;                // k sub-block 0..15
            const int j  = (idx >> 2) & 31;
            const int p  = idx & 3;
            load_lds16(src + (size_t)j * 1024 + kk * 32 + 8 * (p ^ ((j >> 1) & 3)),
                       dst + idx * 16);
        }
    };

    bf16x8 vf[8];
    auto loadV = [&](int jt) {
        const bf16* vs = Vb + (jt << 5);
#pragma unroll
        for (int mf = 0; mf < 8; ++mf)
            vf[mf] = *(const bf16x8*)(vs + (size_t)mf * 16384);
    };

    // Prologue (issue order matters for the vmcnt ledger): K(0), V(0), K(1).
    stageK(0);
    loadV(0);
    SCHED_FENCE();
    stageK(1);

    for (int jt = 0; jt < 32; ++jt) {
        // retire K(jt); leave V(jt), K(jt+1) in flight
        if (jt == 31) WAIT_VM8(); else WAIT_VM16();
        RAW_BARRIER();
        const char* Kt = smem + (jt & 1) * KT;

        // ---- S'[16 j (jh half)][16 i (ih half)] ----
        floatx4 s = (floatx4){0.f, 0.f, 0.f, 0.f};
#pragma unroll
        for (int ks = 0; ks < 16; ++ks) {
            bf16x8 kf = *(const bf16x8*)(Kt + ks * 2048 +
                                         (jh * 16 + laneRow) * 64 + kqs16);
            s = MFMA16(kf, qf[ks], s);
        }

        // ---- exp + rowsum + P write (strip ih, granule (4jh+laneKq)^sw2) ----
        union { bf16 h[4]; unsigned long long u; } w;
#pragma unroll
        for (int r = 0; r < 4; ++r) {
            float v = __expf(s[r] * scale);
            rs += v;
            w.h[r] = __float2bfloat16(v);
        }
        *(unsigned long long*)(plds + ih * 1024 + laneRow * 64 +
                               (((4 * jh + laneKq)) ^ sw2) * 8) = w.u;
        asm volatile("s_waitcnt lgkmcnt(0)" ::: "memory");
        RAW_BARRIER();                   // P visible to all waves
        SCHED_FENCE();
        bf16x8 pf0 = *(const bf16x8*)(plds + laneRow * 64 + kqs16);
        bf16x8 pf1 = *(const bf16x8*)(plds + 1024 + laneRow * 64 + kqs16);

        // retire V(jt); K(jt+1) stays in flight
        if (jt == 31) WAIT_VM0(); else WAIT_VM8();

        // ---- O[c (own 128)][32 i] += V . P ----
        PRIO1();
#pragma unroll
        for (int mf = 0; mf < 8; ++mf) {
            acc[mf][0] = MFMA16(vf[mf], pf0, acc[mf][0]);
            acc[mf][1] = MFMA16(vf[mf], pf1, acc[mf][1]);
        }
        PRIO0();

        RAW_BARRIER();                   // K(jt)/P reads done -> safe restage
        if (jt + 1 < 32) loadV(jt + 1);
        SCHED_FENCE();
        if (jt + 2 < 32) stageK(jt + 2);
    }

    // rowsum: lane partial covers j in {16jh + 4laneKq .. +4} for its row.
    // xor-reduce over laneKq, then sum jh halves via LDS.
    rs += __shfl_xor(rs, 16);
    rs += __shfl_xor(rs, 32);
    if (lane < 16) rsLDS[jh][ih * 16 + lane] = rs;
    __syncthreads();

    // O2[i][c] = acc * ri ; c = wave*128 + mf*16 + 4laneKq + r, i = 16ni+laneRow
#pragma unroll
    for (int ni = 0; ni < 2; ++ni) {
        const int row = ni * 16 + laneRow;
        const float ri = 1.f / (rsLDS[0][row] + rsLDS[1][row]);
        bf16* Ob = O2 + (size_t)b * 524288 +
                   (size_t)(i0 + row) * 512 + wave * 128 + (laneKq << 2);
#pragma unroll
        for (int mf = 0; mf < 8; ++mf) {
            union { bf16 h[4]; ushort4 u; } pk;
#pragma unroll
            for (int r = 0; r < 4; ++r)
                pk.h[r] = __float2bfloat16(acc[mf][ni][r] * ri);
            *(ushort4*)(Ob + mf * 16) = pk.u;
        }
    }
}

// ---------------------------------------------------------------------------
// GroupNorm stats: one block per (b, g); 16 ch x 1024 = 16384 contiguous floats
// ---------------------------------------------------------------------------
__global__ __launch_bounds__(256) void gn_stats(const float* __restrict__ x,
                                                float* __restrict__ stats)
{
    const int bg = blockIdx.x;
    const float4* p = (const float4*)(x + (size_t)bg * 16384);
    float s = 0.f, ss = 0.f;
    for (int i = threadIdx.x; i < 4096; i += 256) {
        float4 v = p[i];
        s  += v.x + v.y + v.z + v.w;
        ss += v.x * v.x + v.y * v.y + v.z * v.z + v.w * v.w;
    }
#pragma unroll
    for (int off = 32; off; off >>= 1) {
        s  += __shfl_down(s, off);
        ss += __shfl_down(ss, off);
    }
    __shared__ float rsm[4], rss[4];
    const int wv = threadIdx.x >> 6;
    if ((threadIdx.x & 63) == 0) { rsm[wv] = s; rss[wv] = ss; }
    __syncthreads();
    if (threadIdx.x == 0) {
        float S  = rsm[0] + rsm[1] + rsm[2] + rsm[3];
        float SS = rss[0] + rss[1] + rss[2] + rss[3];
        float mean = S * (1.f / 16384.f);
        float var  = SS * (1.f / 16384.f) - mean * mean;
        stats[2 * bg]     = mean;
        stats[2 * bg + 1] = rsqrtf(var + EPS);
    }
}

// ---------------------------------------------------------------------------
// GN apply + transpose: x (B,512,1024) fp32 -> xnT (B,1024,512) bf16
// ---------------------------------------------------------------------------
__global__ __launch_bounds__(256) void gn_apply_t(const float* __restrict__ x,
                                                  const float* __restrict__ stats,
                                                  const float* __restrict__ gamma,
                                                  const float* __restrict__ beta,
                                                  bf16* __restrict__ xnT)
{
    __shared__ bf16 tile[32][36];
    const int b = blockIdx.z, c0 = blockIdx.y * 32, i0 = blockIdx.x * 32;
    {
        const int cc = threadIdx.x >> 3;
        const int i4 = (threadIdx.x & 7) << 2;
        const int c  = c0 + cc;
        const float mean = stats[2 * ((b << 5) + (c >> 4))];
        const float rstd = stats[2 * ((b << 5) + (c >> 4)) + 1];
        const float a  = gamma[c] * rstd;
        const float bb = beta[c] - mean * a;
        float4 v = *(const float4*)(x + (((size_t)(b * 512 + c)) << 10) + i0 + i4);
        tile[cc][i4 + 0] = __float2bfloat16(v.x * a + bb);
        tile[cc][i4 + 1] = __float2bfloat16(v.y * a + bb);
        tile[cc][i4 + 2] = __float2bfloat16(v.z * a + bb);
        tile[cc][i4 + 3] = __float2bfloat16(v.w * a + bb);
    }
    __syncthreads();
    {
        const int ii = threadIdx.x >> 3;
        const int c4 = (threadIdx.x & 7) << 2;
        union { bf16 h[4]; uint2 u; } pk;
        pk.h[0] = tile[c4 + 0][ii];
        pk.h[1] = tile[c4 + 1][ii];
        pk.h[2] = tile[c4 + 2][ii];
        pk.h[3] = tile[c4 + 3][ii];
        *((uint2*)(xnT + (((size_t)(b * 1024 + i0 + ii)) << 9) + c0 + c4)) = pk.u;
    }
}

// ---------------------------------------------------------------------------
// prep: weights fp32->bf16 (blocks 0..1023), qkv bias concat (block 1024).
// ---------------------------------------------------------------------------
__global__ __launch_bounds__(256) void prep(
    const float* __restrict__ wq, const float* __restrict__ wk,
    const float* __restrict__ wv, const float* __restrict__ wp,
    bf16* __restrict__ wqkvb, bf16* __restrict__ wpb,
    const float* __restrict__ bq, const float* __restrict__ bk,
    const float* __restrict__ bv, float* __restrict__ bqkv)
{
    const int id = blockIdx.x;
    if (id < 1024) {
        const int w = id >> 8;
        const float* src = (w == 0) ? wq : (w == 1) ? wk : (w == 2) ? wv : wp;
        bf16* dst = (w < 3) ? (wqkvb + (size_t)w * 262144) : wpb;
        const int g = (id & 255) * 256 + threadIdx.x;
        float4 v = ((const float4*)src)[g];
        union { bf16 h[4]; uint2 u; } pk;
        pk.h[0] = __float2bfloat16(v.x);
        pk.h[1] = __float2bfloat16(v.y);
        pk.h[2] = __float2bfloat16(v.z);
        pk.h[3] = __float2bfloat16(v.w);
        ((uint2*)dst)[g] = pk.u;
    } else {
        for (int t = threadIdx.x; t < 1536; t += 256)
            bqkv[t] = (t < 512) ? bq[t] : (t < 1024) ? bk[t - 512] : bv[t - 1024];
    }
}

// ---------------------------------------------------------------------------
extern "C" void kernel_launch(void* const* d_in, const int* in_sizes, int n_in,
                              void* d_out, int out_size, void* d_ws, size_t ws_size,
                              hipStream_t stream)
{
    const float* x     = (const float*)d_in[0];
    const float* gamma = (const float*)d_in[1];
    const float* beta  = (const float*)d_in[2];
    const float* wq    = (const float*)d_in[3];
    const float* bq    = (const float*)d_in[4];
    const float* wk    = (const float*)d_in[5];
    const float* bk    = (const float*)d_in[6];
    const float* wv    = (const float*)d_in[7];
    const float* bv    = (const float*)d_in[8];
    const float* wp    = (const float*)d_in[9];
    const float* bp    = (const float*)d_in[10];
    float* out = (float*)d_out;

    char* ws = (char*)d_ws;
    size_t off = 0;
    auto alloc = [&](size_t bytes) -> char* {
        char* p = ws + off;
        off += (bytes + 255) & ~(size_t)255;
        return p;
    };

    const long long S  = 1024, C = 512;
    const long long BS = S * C;
    const long long ES = S * S;

    float* stats  = (float*)alloc(512 * 2 * sizeof(float));
    float* bqkv   = (float*)alloc(1536 * sizeof(float));
    bf16* wqkvb = (bf16*)alloc((size_t)3 * C * C * 2);  // [wq; wk; wv]
    bf16* wpb   = (bf16*)alloc((size_t)C * C * 2);
    bf16* xnT   = (bf16*)alloc((size_t)16 * BS * 2);
    bf16* qkT   = (bf16*)alloc((size_t)16 * ES * 2);    // (B,1024,1024): [qT|kT]
    bf16* vv    = (bf16*)alloc((size_t)16 * BS * 2);    // (B,512,1024)
    bf16* O2    = (bf16*)alloc((size_t)16 * BS * 2);

    // Dynamic LDS caps (immediate module state; graph-capture safe).
    hipFuncSetAttribute((const void*)gemm2b<2, 0, 1, bf16>,
                        hipFuncAttributeMaxDynamicSharedMemorySize, 65536);
    hipFuncSetAttribute((const void*)gemm2b<1, 1, 0, float>,
                        hipFuncAttributeMaxDynamicSharedMemorySize, 65536);
    hipFuncSetAttribute((const void*)fattn,
                        hipFuncAttributeMaxDynamicSharedMemorySize, 65536);

    prep<<<1025, 256, 0, stream>>>(wq, wk, wv, wp, wqkvb, wpb, bq, bk, bv, bqkv);

    gn_stats<<<512, 256, 0, stream>>>(x, stats);
    gn_apply_t<<<dim3(32, 16, 16), 256, 0, stream>>>(x, stats, gamma, beta, xnT);

    // QKV proj: M=1024 (i), N=1536 ([q|k|v]), K=512, Z=16. 8x12x16 = 1536 blk.
    gemm2b<2, 0, 1, bf16><<<1536, 256, 65536, stream>>>(
        xnT, BS, 512, wqkvb, 0, 512, qkT, ES, 1024, vv, BS,
        bqkv, nullptr, 0, 0, 512, /*tpb*/96, /*gx*/12);

    const float scale = 0.044194173824159216f; // 512^-0.5
    // Fused attention: 16 batches x 32 i-tiles (32 rows) = 512 blocks, 2/CU.
    fattn<<<512, 256, 65536, stream>>>(qkT, vv, O2, scale);

    // out[o][i] = sum_c wp[o][c] O2[i][c] + bp[o] + x[o][i]. 4x8 tiles x16.
    gemm2b<1, 1, 0, float><<<512, 256, 65536, stream>>>(
        wpb, 0, 512, O2, BS, 512, out, BS, 1024, nullptr, 0,
        bp, x, BS, 1024, 512, /*tpb*/32, /*gx*/8);
}

// Round 10
// 227.940 us; speedup vs baseline: 1.1948x; 1.1948x over previous
//
#include <hip/hip_runtime.h>
#include <hip/hip_bf16.h>

using bf16 = __hip_bfloat16;

typedef __attribute__((ext_vector_type(8))) __bf16 bf16x8;
typedef __attribute__((ext_vector_type(4))) float floatx4;

#define EPS 1e-6f

#define RAW_BARRIER()  asm volatile("s_barrier" ::: "memory")
#define WAIT_VM8()     asm volatile("s_waitcnt vmcnt(8)" ::: "memory")
#define WAIT_VM4()     asm volatile("s_waitcnt vmcnt(4)" ::: "memory")
#define WAIT_VM0()     asm volatile("s_waitcnt vmcnt(0)" ::: "memory")
#define SCHED_FENCE()  __builtin_amdgcn_sched_barrier(0)
#define PRIO1()        __builtin_amdgcn_s_setprio(1)
#define PRIO0()        __builtin_amdgcn_s_setprio(0)

__device__ __forceinline__ void load_lds16(const void* g, void* l) {
    __builtin_amdgcn_global_load_lds(
        (const __attribute__((address_space(1))) void*)g,
        (__attribute__((address_space(3))) void*)l, 16, 0, 0);
}

__device__ __forceinline__ void storeOut(float* p, float v) { *p = v; }
__device__ __forceinline__ void storeOut(bf16* p, float v) { *p = __float2bfloat16(v); }

#define MFMA16(a, b, c) __builtin_amdgcn_mfma_f32_16x16x32_bf16(a, b, c, 0, 0, 0)

// ---------------------------------------------------------------------------
// 2-blocks/CU pipelined NT GEMM: D[m][n] = sum_k A[m][k] * B[n][k]
// BM=BN=128, BK=64 (k-half split), 256 threads = 4 waves (2M x 2N).
// (Unchanged — used for QKV projection and output projection.)
// ---------------------------------------------------------------------------
template <int BIAS_MODE, int RESID_EN, int QKV, typename OutT>
__global__ __launch_bounds__(256, 2) void gemm2b(
    const bf16* __restrict__ A, long long aStride, int lda,
    const bf16* __restrict__ B, long long bStride, int ldb,
    OutT* __restrict__ D, long long dStride, int ldd,
    bf16* __restrict__ vout, long long vStride,
    const float* __restrict__ bias,
    const float* __restrict__ resid, long long rStride, int ldr,
    int K, int tpb, int gx)
{
    constexpr int HB = 8192;   // bytes per (buf, khalf) per operand: 128x32x2B
    extern __shared__ char smem[];

    const unsigned chunk = gridDim.x >> 3;
    const unsigned glob  = (blockIdx.x & 7) * chunk + (blockIdx.x >> 3);
    const unsigned z  = glob / (unsigned)tpb;
    const unsigned t  = glob % (unsigned)tpb;
    const int m0 = (int)(t / (unsigned)gx) << 7;
    const int n0 = (int)(t % (unsigned)gx) << 7;

    const int tid  = threadIdx.x;
    const int lane = tid & 63;
    const int wave = tid >> 6;
    const int wm   = wave >> 1;          // 0..1
    const int wn   = wave & 1;           // 0..1

    const bf16* Ab = A + (size_t)z * aStride + (size_t)m0 * lda;
    const bf16* Bb = B + (size_t)z * bStride + (size_t)n0 * ldb;

    floatx4 acc[4][4];
#pragma unroll
    for (int i = 0; i < 4; ++i)
#pragma unroll
        for (int j = 0; j < 4; ++j) acc[i][j] = (floatx4){0.f, 0.f, 0.f, 0.f};

    const int laneRow = lane & 15;
    const int laneKq  = lane >> 4;
    const int kqs16   = (laneKq ^ ((laneRow >> 1) & 3)) << 4;
    const int arow0   = wm * 64 + laneRow;
    const int brow0   = wn * 64 + laneRow;

    auto stage = [&](int kt, int h) {
        char* Adst = smem + ((kt & 1) * 2 + h) * HB;
        char* Bdst = smem + 4 * HB + ((kt & 1) * 2 + h) * HB;
        const int kb = (kt << 6) + (h << 5);
#pragma unroll
        for (int u = 0; u < 2; ++u) {
            const int idx = tid + u * 256;
            const int r  = idx >> 2;
            const int qs = (idx & 3) ^ ((idx >> 3) & 3);
            load_lds16(Ab + (size_t)r * lda + kb + qs * 8, Adst + idx * 16);
        }
#pragma unroll
        for (int u = 0; u < 2; ++u) {
            const int idx = tid + u * 256;
            const int r  = idx >> 2;
            const int qs = (idx & 3) ^ ((idx >> 3) & 3);
            load_lds16(Bb + (size_t)r * ldb + kb + qs * 8, Bdst + idx * 16);
        }
    };

    const int nt = K >> 6;
    stage(0, 0); stage(0, 1); stage(1, 0);

    for (int kt = 0; kt < nt; ++kt) {
        const char* Ablk = smem + (kt & 1) * 2 * HB;
        const char* Bblk = smem + 4 * HB + (kt & 1) * 2 * HB;
        const bool lastT = (kt == nt - 1);

        // ---- phase 1: k-half 0 ----
        if (lastT) WAIT_VM4(); else WAIT_VM8();
        RAW_BARRIER();
        bf16x8 af[4], bfr[4];
#pragma unroll
        for (int im = 0; im < 4; ++im)
            af[im] = *(const bf16x8*)(Ablk + (arow0 + im * 16) * 64 + kqs16);
#pragma unroll
        for (int in = 0; in < 4; ++in)
            bfr[in] = *(const bf16x8*)(Bblk + (brow0 + in * 16) * 64 + kqs16);
        if (kt + 1 < nt) stage(kt + 1, 1);
        RAW_BARRIER();
        PRIO1();
#pragma unroll
        for (int im = 0; im < 4; ++im)
#pragma unroll
            for (int in = 0; in < 4; ++in)
                acc[im][in] = MFMA16(af[im], bfr[in], acc[im][in]);
        PRIO0();

        // ---- phase 2: k-half 1 ----
        if (lastT) WAIT_VM0(); else WAIT_VM8();
        RAW_BARRIER();
#pragma unroll
        for (int im = 0; im < 4; ++im)
            af[im] = *(const bf16x8*)(Ablk + HB + (arow0 + im * 16) * 64 + kqs16);
#pragma unroll
        for (int in = 0; in < 4; ++in)
            bfr[in] = *(const bf16x8*)(Bblk + HB + (brow0 + in * 16) * 64 + kqs16);
        if (kt + 2 < nt) stage(kt + 2, 0);
        RAW_BARRIER();
        PRIO1();
#pragma unroll
        for (int im = 0; im < 4; ++im)
#pragma unroll
            for (int in = 0; in < 4; ++in)
                acc[im][in] = MFMA16(af[im], bfr[in], acc[im][in]);
        PRIO0();
    }

    // Epilogue. C/D frag layout: col = lane&15, row = (lane>>4)*4 + reg
    const size_t dbase = (size_t)z * dStride;
#pragma unroll
    for (int im = 0; im < 4; ++im) {
        const int gmb = m0 + wm * 64 + im * 16 + (laneKq << 2);
#pragma unroll
        for (int in = 0; in < 4; ++in) {
            const int gn = n0 + wn * 64 + in * 16 + laneRow;
            float bn = 0.f;
            if (BIAS_MODE == 2) bn = bias[gn];
            if (QKV && n0 >= 1024) {
                union { bf16 h[4]; ushort4 u; } pk;
#pragma unroll
                for (int r = 0; r < 4; ++r)
                    pk.h[r] = __float2bfloat16(acc[im][in][r] + bn);
                *(ushort4*)(vout + (size_t)z * vStride +
                            (size_t)(gn - 1024) * 1024 + gmb) = pk.u;
            } else {
#pragma unroll
                for (int r = 0; r < 4; ++r) {
                    const int gm = gmb + r;
                    float v = acc[im][in][r];
                    if (BIAS_MODE == 1) v += bias[gm];
                    if (BIAS_MODE == 2) v += bn;
                    if (RESID_EN)
                        v += resid[(size_t)z * rStride + (size_t)gm * ldr + gn];
                    storeOut(D + dbase + (size_t)gm * ldd + gn, v);
                }
            }
        }
    }
}

// ---------------------------------------------------------------------------
// Fused attention v6 = v4 (74.2us, proven, passing) with 8 waves/block.
//   S'[j][i] = K_j . Q_i (swapped), P = exp(scale*S'), rowsum[i] += P,
//   O[c][i] += V[c][j] * P[j][i], O2[i][c] = O / rowsum.
// v4 was latency-bound at 1 wave/SIMD (Occ 10%): 5566 cy/tile vs ~2800 LDS
// model — ds_read latency + serial MFMA chains + exp all unhidden.
// v5 (2 blocks/CU) REGRESSED (108us): each block staged its own K copy
// (2x L2->LDS traffic) + V via L2 — occupancy bought by duplicating data
// movement. v6 gets 2 waves/SIMD with ZERO extra data movement: same block
// size (64 q-rows), same 128KB K+V double-buffered staging (one pass/CU),
// but 512 threads = 8 waves:
//  - QK split (jh = wave&1, ih = wave>>2... wave>>1): wave computes
//    S'[16 j (jh)][16 i (ih)], 16 kf reads + one 16-chain. Per-CU kf reads
//    unchanged (8x16 = v4's 4x32 = 128/tile).
//  - P write: strip ih, row laneRow, granule (4jh+laneKq)^sw2 — the exact
//    mapping verified correct in v5 (passed absmax). Read side = v4
//    verbatim (pf[ni] at kqs16).
//  - PV c-split 8-ways: wave owns c in [64w..64w+64): 4 vf reads/tile
//    (per-CU 32, same as v4), each reused over 4 MFMAs. acc[4][4] = 64 f32.
//  - Staging lambdas identical (2048 slots; 4 iters/thread at 512 thr).
//    vmcnt ledger: 8 staged loads/thread/tile; prologue 16; top-of-loop
//    vmcnt(8) retires tile jt (leaves jt+1's 8); jt=31 vmcnt(0). Bottom
//    barrier then stage jt+2 (WAR-safe, v4 scheme).
// Register/wave: qf 64 + pf 16 + temps (~110 arch) + acc 64 AGPR -> 2
// waves/SIMD fit trivially under launch_bounds(512,2).
// ---------------------------------------------------------------------------
__global__ __launch_bounds__(512, 2) void fattn(
    const bf16* __restrict__ qkT,   // (B,1024,1024): row i = [q_i | k_i]
    const bf16* __restrict__ vv,    // (B,512,1024): [c][j]
    bf16* __restrict__ O2,          // (B,1024,512): [i][c]
    float scale)
{
    constexpr int KT = 32768;           // one K- or V-tile: 32KB
    extern __shared__ char smem[];      // [2]K + [2]V = 128KB
    __shared__ __align__(16) char plds[4 * 1024];   // P: 4 strips [16 i][32 j]
    __shared__ float rsLDS[2][64];

    const int bid  = blockIdx.x;
    const int glob = (bid & 7) * 32 + (bid >> 3);   // XCD-chunked (256 blocks)
    const int b    = glob >> 4;
    const int i0   = (glob & 15) << 6;

    const int tid     = threadIdx.x;
    const int lane    = tid & 63;
    const int wave    = tid >> 6;       // 0..7
    const int jh      = wave & 1;       // j-half owner in QK
    const int ih      = wave >> 1;      // i-quarter owner in QK (0..3)
    const int laneRow = lane & 15;
    const int laneKq  = lane >> 4;
    const int kqs16   = (laneKq ^ ((laneRow >> 1) & 3)) << 4;
    const int sw2     = ((laneRow >> 1) & 3) << 1;  // 8B-granule XOR mask

    const bf16* Qb = qkT + (size_t)b * 1048576 +
                     (size_t)(i0 + ih * 16 + laneRow) * 1024;
    const bf16* Kb = qkT + (size_t)b * 1048576 + 512;
    const bf16* Vb = vv + (size_t)b * 524288;

    // Q fragments: i = i0 + 16*ih + laneRow, k = ks*32 + laneKq*8..+8
    bf16x8 qf[16];
#pragma unroll
    for (int ks = 0; ks < 16; ++ks)
        qf[ks] = *(const bf16x8*)(Qb + ks * 32 + laneKq * 8);

    // acc[mf][ni]: c = wave*64 + mf*16 + 4*laneKq + r, i = 16*ni + laneRow
    floatx4 acc[4][4];
#pragma unroll
    for (int mf = 0; mf < 4; ++mf)
#pragma unroll
        for (int ni = 0; ni < 4; ++ni) acc[mf][ni] = (floatx4){0.f, 0.f, 0.f, 0.f};
    float rs = 0.f;

    auto stageK = [&](int jt) {
        char* dst = smem + (jt & 1) * KT;
        const bf16* src = Kb + ((size_t)jt << 5) * 1024;
#pragma unroll
        for (int u = 0; u < 4; ++u) {
            const int idx = tid + u * 512;          // 0..2047
            const int kk = idx >> 7;                // k sub-block 0..15
            const int j  = (idx >> 2) & 31;
            const int p  = idx & 3;
            load_lds16(src + (size_t)j * 1024 + kk * 32 + 8 * (p ^ ((j >> 1) & 3)),
                       dst + idx * 16);
        }
    };
    auto stageV = [&](int jt) {
        char* dst = smem + 2 * KT + (jt & 1) * KT;
        const bf16* src = Vb + (jt << 5);
#pragma unroll
        for (int u = 0; u < 4; ++u) {
            const int idx = tid + u * 512;
            const int c = idx >> 2;                 // 0..511
            const int p = idx & 3;
            load_lds16(src + (size_t)c * 1024 + 8 * (p ^ ((c >> 1) & 3)),
                       dst + idx * 16);
        }
    };

    stageK(0); stageV(0); stageK(1); stageV(1);     // 16 outstanding/thread

    for (int jt = 0; jt < 32; ++jt) {
        // retire tile jt's K+V (8 loads); leave tile jt+1's 8 in flight
        if (jt == 31) WAIT_VM0(); else WAIT_VM8();
        RAW_BARRIER();
        const char* Kt = smem + (jt & 1) * KT;
        const char* Vt = smem + 2 * KT + (jt & 1) * KT;

        // ---- S'[16 j (jh)][16 i (ih)] ----
        floatx4 s = (floatx4){0.f, 0.f, 0.f, 0.f};
#pragma unroll
        for (int ks = 0; ks < 16; ++ks) {
            bf16x8 kf = *(const bf16x8*)(Kt + ks * 2048 +
                                         (jh * 16 + laneRow) * 64 + kqs16);
            s = MFMA16(kf, qf[ks], s);
        }

        // ---- exp + rowsum + P write (strip ih, granule (4jh+laneKq)^sw2) ----
        union { bf16 h[4]; unsigned long long u; } w;
#pragma unroll
        for (int r = 0; r < 4; ++r) {
            float v = __expf(s[r] * scale);
            rs += v;
            w.h[r] = __float2bfloat16(v);
        }
        *(unsigned long long*)(plds + ih * 1024 + laneRow * 64 +
                               ((4 * jh + laneKq) ^ sw2) * 8) = w.u;
        asm volatile("s_waitcnt lgkmcnt(0)" ::: "memory");
        RAW_BARRIER();                   // P visible to all waves
        SCHED_FENCE();
        bf16x8 pf[4];
#pragma unroll
        for (int ni = 0; ni < 4; ++ni)
            pf[ni] = *(const bf16x8*)(plds + ni * 1024 + laneRow * 64 + kqs16);

        // ---- O[c (own 64)][all 64 i] += V . P ----
        PRIO1();
#pragma unroll
        for (int mf = 0; mf < 4; ++mf) {
            bf16x8 vf = *(const bf16x8*)(Vt +
                (wave * 64 + mf * 16 + laneRow) * 64 + kqs16);
#pragma unroll
            for (int ni = 0; ni < 4; ++ni)
                acc[mf][ni] = MFMA16(vf, pf[ni], acc[mf][ni]);
        }
        PRIO0();

        RAW_BARRIER();                   // K/V(jt) + P reads done
        if (jt + 2 < 32) { stageK(jt + 2); stageV(jt + 2); }
    }

    // rowsum: lane partial covers its 4 j-regs; xor-reduce over laneKq
    // groups -> per (i = laneRow, jh, ih); sum jh halves via LDS.
    rs += __shfl_xor(rs, 16);
    rs += __shfl_xor(rs, 32);
    if (lane < 16) rsLDS[jh][ih * 16 + lane] = rs;
    __syncthreads();

    // O2[i][c] = acc * ri ; c = wave*64 + mf*16 + 4laneKq + r, i = 16ni+laneRow
#pragma unroll
    for (int ni = 0; ni < 4; ++ni) {
        const int row = ni * 16 + laneRow;
        const float ri = 1.f / (rsLDS[0][row] + rsLDS[1][row]);
        bf16* Ob = O2 + (size_t)b * 524288 +
                   (size_t)(i0 + row) * 512 + wave * 64 + (laneKq << 2);
#pragma unroll
        for (int mf = 0; mf < 4; ++mf) {
            union { bf16 h[4]; ushort4 u; } pk;
#pragma unroll
            for (int r = 0; r < 4; ++r)
                pk.h[r] = __float2bfloat16(acc[mf][ni][r] * ri);
            *(ushort4*)(Ob + mf * 16) = pk.u;
        }
    }
}

// ---------------------------------------------------------------------------
// GroupNorm stats: one block per (b, g); 16 ch x 1024 = 16384 contiguous floats
// ---------------------------------------------------------------------------
__global__ __launch_bounds__(256) void gn_stats(const float* __restrict__ x,
                                                float* __restrict__ stats)
{
    const int bg = blockIdx.x;
    const float4* p = (const float4*)(x + (size_t)bg * 16384);
    float s = 0.f, ss = 0.f;
    for (int i = threadIdx.x; i < 4096; i += 256) {
        float4 v = p[i];
        s  += v.x + v.y + v.z + v.w;
        ss += v.x * v.x + v.y * v.y + v.z * v.z + v.w * v.w;
    }
#pragma unroll
    for (int off = 32; off; off >>= 1) {
        s  += __shfl_down(s, off);
        ss += __shfl_down(ss, off);
    }
    __shared__ float rsm[4], rss[4];
    const int wv = threadIdx.x >> 6;
    if ((threadIdx.x & 63) == 0) { rsm[wv] = s; rss[wv] = ss; }
    __syncthreads();
    if (threadIdx.x == 0) {
        float S  = rsm[0] + rsm[1] + rsm[2] + rsm[3];
        float SS = rss[0] + rss[1] + rss[2] + rss[3];
        float mean = S * (1.f / 16384.f);
        float var  = SS * (1.f / 16384.f) - mean * mean;
        stats[2 * bg]     = mean;
        stats[2 * bg + 1] = rsqrtf(var + EPS);
    }
}

// ---------------------------------------------------------------------------
// GN apply + transpose: x (B,512,1024) fp32 -> xnT (B,1024,512) bf16
// ---------------------------------------------------------------------------
__global__ __launch_bounds__(256) void gn_apply_t(const float* __restrict__ x,
                                                  const float* __restrict__ stats,
                                                  const float* __restrict__ gamma,
                                                  const float* __restrict__ beta,
                                                  bf16* __restrict__ xnT)
{
    __shared__ bf16 tile[32][36];
    const int b = blockIdx.z, c0 = blockIdx.y * 32, i0 = blockIdx.x * 32;
    {
        const int cc = threadIdx.x >> 3;
        const int i4 = (threadIdx.x & 7) << 2;
        const int c  = c0 + cc;
        const float mean = stats[2 * ((b << 5) + (c >> 4))];
        const float rstd = stats[2 * ((b << 5) + (c >> 4)) + 1];
        const float a  = gamma[c] * rstd;
        const float bb = beta[c] - mean * a;
        float4 v = *(const float4*)(x + (((size_t)(b * 512 + c)) << 10) + i0 + i4);
        tile[cc][i4 + 0] = __float2bfloat16(v.x * a + bb);
        tile[cc][i4 + 1] = __float2bfloat16(v.y * a + bb);
        tile[cc][i4 + 2] = __float2bfloat16(v.z * a + bb);
        tile[cc][i4 + 3] = __float2bfloat16(v.w * a + bb);
    }
    __syncthreads();
    {
        const int ii = threadIdx.x >> 3;
        const int c4 = (threadIdx.x & 7) << 2;
        union { bf16 h[4]; uint2 u; } pk;
        pk.h[0] = tile[c4 + 0][ii];
        pk.h[1] = tile[c4 + 1][ii];
        pk.h[2] = tile[c4 + 2][ii];
        pk.h[3] = tile[c4 + 3][ii];
        *((uint2*)(xnT + (((size_t)(b * 1024 + i0 + ii)) << 9) + c0 + c4)) = pk.u;
    }
}

// ---------------------------------------------------------------------------
// prep: weights fp32->bf16 (blocks 0..1023), qkv bias concat (block 1024).
// ---------------------------------------------------------------------------
__global__ __launch_bounds__(256) void prep(
    const float* __restrict__ wq, const float* __restrict__ wk,
    const float* __restrict__ wv, const float* __restrict__ wp,
    bf16* __restrict__ wqkvb, bf16* __restrict__ wpb,
    const float* __restrict__ bq, const float* __restrict__ bk,
    const float* __restrict__ bv, float* __restrict__ bqkv)
{
    const int id = blockIdx.x;
    if (id < 1024) {
        const int w = id >> 8;
        const float* src = (w == 0) ? wq : (w == 1) ? wk : (w == 2) ? wv : wp;
        bf16* dst = (w < 3) ? (wqkvb + (size_t)w * 262144) : wpb;
        const int g = (id & 255) * 256 + threadIdx.x;
        float4 v = ((const float4*)src)[g];
        union { bf16 h[4]; uint2 u; } pk;
        pk.h[0] = __float2bfloat16(v.x);
        pk.h[1] = __float2bfloat16(v.y);
        pk.h[2] = __float2bfloat16(v.z);
        pk.h[3] = __float2bfloat16(v.w);
        ((uint2*)dst)[g] = pk.u;
    } else {
        for (int t = threadIdx.x; t < 1536; t += 256)
            bqkv[t] = (t < 512) ? bq[t] : (t < 1024) ? bk[t - 512] : bv[t - 1024];
    }
}

// ---------------------------------------------------------------------------
extern "C" void kernel_launch(void* const* d_in, const int* in_sizes, int n_in,
                              void* d_out, int out_size, void* d_ws, size_t ws_size,
                              hipStream_t stream)
{
    const float* x     = (const float*)d_in[0];
    const float* gamma = (const float*)d_in[1];
    const float* beta  = (const float*)d_in[2];
    const float* wq    = (const float*)d_in[3];
    const float* bq    = (const float*)d_in[4];
    const float* wk    = (const float*)d_in[5];
    const float* bk    = (const float*)d_in[6];
    const float* wv    = (const float*)d_in[7];
    const float* bv    = (const float*)d_in[8];
    const float* wp    = (const float*)d_in[9];
    const float* bp    = (const float*)d_in[10];
    float* out = (float*)d_out;

    char* ws = (char*)d_ws;
    size_t off = 0;
    auto alloc = [&](size_t bytes) -> char* {
        char* p = ws + off;
        off += (bytes + 255) & ~(size_t)255;
        return p;
    };

    const long long S  = 1024, C = 512;
    const long long BS = S * C;
    const long long ES = S * S;

    float* stats  = (float*)alloc(512 * 2 * sizeof(float));
    float* bqkv   = (float*)alloc(1536 * sizeof(float));
    bf16* wqkvb = (bf16*)alloc((size_t)3 * C * C * 2);  // [wq; wk; wv]
    bf16* wpb   = (bf16*)alloc((size_t)C * C * 2);
    bf16* xnT   = (bf16*)alloc((size_t)16 * BS * 2);
    bf16* qkT   = (bf16*)alloc((size_t)16 * ES * 2);    // (B,1024,1024): [qT|kT]
    bf16* vv    = (bf16*)alloc((size_t)16 * BS * 2);    // (B,512,1024)
    bf16* O2    = (bf16*)alloc((size_t)16 * BS * 2);

    // Dynamic LDS caps (immediate module state; graph-capture safe).
    hipFuncSetAttribute((const void*)gemm2b<2, 0, 1, bf16>,
                        hipFuncAttributeMaxDynamicSharedMemorySize, 65536);
    hipFuncSetAttribute((const void*)gemm2b<1, 1, 0, float>,
                        hipFuncAttributeMaxDynamicSharedMemorySize, 65536);
    hipFuncSetAttribute((const void*)fattn,
                        hipFuncAttributeMaxDynamicSharedMemorySize, 131072);

    prep<<<1025, 256, 0, stream>>>(wq, wk, wv, wp, wqkvb, wpb, bq, bk, bv, bqkv);

    gn_stats<<<512, 256, 0, stream>>>(x, stats);
    gn_apply_t<<<dim3(32, 16, 16), 256, 0, stream>>>(x, stats, gamma, beta, xnT);

    // QKV proj: M=1024 (i), N=1536 ([q|k|v]), K=512, Z=16. 8x12x16 = 1536 blk.
    gemm2b<2, 0, 1, bf16><<<1536, 256, 65536, stream>>>(
        xnT, BS, 512, wqkvb, 0, 512, qkT, ES, 1024, vv, BS,
        bqkv, nullptr, 0, 0, 512, /*tpb*/96, /*gx*/12);

    const float scale = 0.044194173824159216f; // 512^-0.5
    // Fused attention: 16 batches x 16 i-tiles (64 rows) = 256 blocks,
    // 512 threads = 8 waves = 2 waves/SIMD.
    fattn<<<256, 512, 131072, stream>>>(qkT, vv, O2, scale);

    // out[o][i] = sum_c wp[o][c] O2[i][c] + bp[o] + x[o][i]. 4x8 tiles x16.
    gemm2b<1, 1, 0, float><<<512, 256, 65536, stream>>>(
        wpb, 0, 512, O2, BS, 512, out, BS, 1024, nullptr, 0,
        bp, x, BS, 1024, 512, /*tpb*/32, /*gx*/8);
}